// Round 9
// baseline (287.922 us; speedup 1.0000x reference)
//
#include <hip/hip_runtime.h>
#include <math.h>
#include <stdint.h>

// Problem constants: B=2, S_DEC=2048, S_ENC=2048, D=1024, H=16, HD=64.
// Reference swaps args: Q <- enc_hidden, K/V <- dec_hidden.

typedef unsigned short ushort_t;
typedef __attribute__((ext_vector_type(8))) short short8;    // 8 x bf16 (4 VGPRs)
typedef __attribute__((ext_vector_type(4))) float floatx4;   // MFMA accumulator

__device__ __forceinline__ ushort_t f2bf(float x){
  unsigned u = __float_as_uint(x);
  u += 0x7fffu + ((u >> 16) & 1u);          // RNE
  return (ushort_t)(u >> 16);
}
__device__ __forceinline__ unsigned pk2bf(float a, float b){
#if __has_builtin(__builtin_amdgcn_cvt_pk_bf16_f32)
  typedef __attribute__((ext_vector_type(2))) __bf16 bf2_t;
  bf2_t r = __builtin_amdgcn_cvt_pk_bf16_f32(a, b);
  return *(unsigned*)&r;
#else
  return (unsigned)f2bf(a) | ((unsigned)f2bf(b) << 16);
#endif
}
__device__ __forceinline__ floatx4 mfma16(short8 a, short8 b, floatx4 c){
  return __builtin_amdgcn_mfma_f32_16x16x32_bf16(a, b, c, 0, 0, 0);
}
// direct HBM -> LDS, 16 B per lane; LDS dest = wave-uniform base + lane*16 (linear).
__device__ __forceinline__ void gload16(const void* g, void* l){
  __builtin_amdgcn_global_load_lds((const __attribute__((address_space(1))) void*)g,
                                   (__attribute__((address_space(3))) void*)l, 16, 0, 0);
}

// ---------------- prep: conv + QKV weight transposes ----------------
// ROUND-9: maskpack and WoT moved into gemm_qkv's z=3 plane (both are dependency-free
// w.r.t. gemm_qkv and overlap its compute instead of serializing). 41984 -> 8960 blocks.
// block ranges: [0,8192) conv enc/dec; [8192,8960) QKV weight transpose.
__global__ __launch_bounds__(256)
void prep_kernel(const float* __restrict__ enc, const float* __restrict__ dec,
                 const float* __restrict__ Wq, const float* __restrict__ Wk,
                 const float* __restrict__ Wv,
                 ushort_t* __restrict__ encb, ushort_t* __restrict__ decb,
                 ushort_t* __restrict__ WqT, ushort_t* __restrict__ WkT,
                 ushort_t* __restrict__ WvT)
{
  __shared__ float t[64][65];
  const int bx = blockIdx.x, tid = threadIdx.x;
  if (bx < 8192){                      // fp32 -> bf16 casts
    const float* src = (bx < 4096) ? enc : dec;
    ushort_t*    dst = (bx < 4096) ? encb : decb;
    int i = ((bx & 4095) * 256 + tid) * 4;
    const float4 v = *(const float4*)(src + i);
    unsigned long long p = (unsigned long long)pk2bf(v.x, v.y)
                         | ((unsigned long long)pk2bf(v.z, v.w) << 32);
    *(unsigned long long*)(dst + i) = p;
  } else {                             // QKV weight transpose: Wx[h][1024 d][64 k] -> WxT[(h*64+k)][1024 d]
    const int id = bx - 8192;          // 768 = 48 z * 16 y
    const int zz = id >> 4, yy = id & 15;
    const int which = zz >> 4, head = zz & 15;
    const float* src = (which == 0) ? Wq : (which == 1) ? Wk : Wv;
    ushort_t*    dst = (which == 0) ? WqT : (which == 1) ? WkT : WvT;
    const long sb = (long)head * 65536;
    const int r0 = yy * 64;
    #pragma unroll
    for (int i = 0; i < 4; i++){       // 1024 float4-chunks = 64 rows x 16 chunks
      int idx = i*256 + tid;
      int r = idx >> 4, c4 = idx & 15;
      const float4 v = *(const float4*)&src[sb + (long)(r0 + r)*64 + c4*4];
      t[r][c4*4+0] = v.x; t[r][c4*4+1] = v.y;
      t[r][c4*4+2] = v.z; t[r][c4*4+3] = v.w;
    }
    __syncthreads();
    #pragma unroll
    for (int i = 0; i < 4; i++){       // 1024 u64-chunks = 64 cols x 16 row-quads
      int idx = i*256 + tid;
      int cr = idx >> 4, rq = idx & 15;
      unsigned long long p =
          (unsigned long long)pk2bf(t[rq*4+0][cr], t[rq*4+1][cr])
        | ((unsigned long long)pk2bf(t[rq*4+2][cr], t[rq*4+3][cr]) << 32);
      *(unsigned long long*)&dst[sb + (long)cr*1024 + r0 + rq*4] = p;
    }
  }
}

// ---------------- fused QKV projection GEMM + overlapped maskpack/WoT (z=3) ----------------
// grid (32 m, 8 n, 4). z=0: Q = (enc*WqT+bq)*Cscale; z=1: K = dec*WkT+bk; z=2: remapped
// 8x16x2 computing V^T = WvT*dec^T + bv (out [bh][64][2048]).
// z=3 (ROUND-9): 256 light blocks overlapping the 768 compute blocks — id<224 maskpack
// (mask -> bitmask, needed only by flash which runs later), id>=224 WoT transpose (needed
// only by gemm_o). Memory-bound work fills idle BW behind the compute-bound gemm.
// blockIdx.x = m-index -> XCD = bx%8 stripes M: per-XCD A-panel ~1 MB + weights 2 MB, L2-resident.
__global__ __launch_bounds__(256, 3)
void gemm_qkv_kernel(const ushort_t* __restrict__ encb, const ushort_t* __restrict__ decb,
                     const ushort_t* __restrict__ WqT, const ushort_t* __restrict__ WkT,
                     const ushort_t* __restrict__ WvT,
                     const float* __restrict__ bq, const float* __restrict__ bk,
                     const float* __restrict__ bv,
                     ushort_t* __restrict__ Qb, ushort_t* __restrict__ Kbf,
                     ushort_t* __restrict__ Vtb,
                     const int* __restrict__ mask, unsigned long long* __restrict__ mbq,
                     const float* __restrict__ Wo, ushort_t* __restrict__ WoT)
{
  __shared__ __align__(16) unsigned char qsmem[32768];   // At/Bt for gemm; float[64][65] for WoT
  ushort_t* At = (ushort_t*)qsmem;            // 2*4096 shorts
  ushort_t* Bt = (ushort_t*)(qsmem + 16384);  // 2*4096 shorts
  const int tid = threadIdx.x;
  const int z = blockIdx.z;

  if (z == 3){
    const int id = blockIdx.x*8 + blockIdx.y;   // 0..255
    if (id < 224){                              // maskpack: bit s of u64 word (b*2048+q)*32 + s/64
      const long total = 8388608;               // B*S_ENC*S_DEC
      for (long g = (long)id*256 + tid; g < total; g += 224*256){
        unsigned long long bal = __ballot(mask[g] != 0);
        if ((tid & 63) == 0) mbq[g >> 6] = bal;
      }
    } else {                                    // WoT: Wo[1024 d][1024 e] -> WoT[e][d], 8 tiles/block
      float (*t)[65] = (float(*)[65])qsmem;     // 64*65*4 = 16640 B <= 32768
      for (int j = 0; j < 8; j++){
        const int tl = (id - 224)*8 + j;        // 0..255 tile id
        const int r0 = (tl >> 4) * 64, c0 = (tl & 15) * 64;
        #pragma unroll
        for (int i = 0; i < 4; i++){
          int idx = i*256 + tid;
          int r = idx >> 4, c4 = idx & 15;
          const float4 v = *(const float4*)&Wo[(long)(r0 + r)*1024 + c0 + c4*4];
          t[r][c4*4+0] = v.x; t[r][c4*4+1] = v.y;
          t[r][c4*4+2] = v.z; t[r][c4*4+3] = v.w;
        }
        __syncthreads();
        #pragma unroll
        for (int i = 0; i < 4; i++){
          int idx = i*256 + tid;
          int cr = idx >> 4, rq = idx & 15;
          unsigned long long p =
              (unsigned long long)pk2bf(t[rq*4+0][cr], t[rq*4+1][cr])
            | ((unsigned long long)pk2bf(t[rq*4+2][cr], t[rq*4+3][cr]) << 32);
          *(unsigned long long*)&WoT[(long)(c0 + cr)*1024 + r0 + rq*4] = p;
        }
        __syncthreads();
      }
    }
    return;
  }

  const int wave = tid >> 6, lane = tid & 63;
  const int quad = lane >> 4, l16 = lane & 15;
  const ushort_t *A, *BT; const float* bias; ushort_t* outp;
  int m0, n0; long outAdj = 0;
  float qs = 1.0f;
  if (z == 0){ A = encb; BT = WqT; bias = bq; outp = Qb;  m0 = blockIdx.x*128; n0 = blockIdx.y*128;
               qs = 0.18033688011112042f; }   // log2(e)/sqrt(64) folded into Q
  else if (z == 1){ A = decb; BT = WkT; bias = bk; outp = Kbf; m0 = blockIdx.x*128; n0 = blockIdx.y*128; }
  else {
    int id = blockIdx.x*8 + blockIdx.y;     // 0..255
    int vb = id >> 7, rem = id & 127;
    m0 = ((rem >> 4) & 7) * 128; n0 = (rem & 15) * 128;
    A = WvT; BT = decb + (long)vb*2097152; bias = bv; outp = Vtb; outAdj = (long)vb*2097152;
  }
  const int K = 1024;

  const int c0 = tid, c1 = 256 + tid;   // chunk -> row c>>2, col-chunk (c&3)*8 of [128][32] tile
  const ushort_t* gA0 = A  + (long)(m0 + (c0 >> 2))*K + (c0 & 3)*8;
  const ushort_t* gA1 = A  + (long)(m0 + (c1 >> 2))*K + (c1 & 3)*8;
  const ushort_t* gB0 = BT + (long)(n0 + (c0 >> 2))*K + (c0 & 3)*8;
  const ushort_t* gB1 = BT + (long)(n0 + (c1 >> 2))*K + (c1 & 3)*8;

  floatx4 acc[4][4];
  #pragma unroll
  for (int mt = 0; mt < 4; mt++)
    #pragma unroll
    for (int nt = 0; nt < 4; nt++)
      acc[mt][nt] = (floatx4){0.f, 0.f, 0.f, 0.f};

  // prologue: issue tile-0 loads into buf 0 (wave-uniform LDS dest + lane*16)
  {
    char* Ad = (char*)At + wave*1024;
    char* Bd = (char*)Bt + wave*1024;
    gload16(gA0, Ad); gload16(gA1, Ad + 4096);
    gload16(gB0, Bd); gload16(gB1, Bd + 4096);
    gA0 += 32; gA1 += 32; gB0 += 32; gB1 += 32;
  }

  const int moff = (wave & 1) * 64, noff = (wave >> 1) * 64;
  int cur = 0;
  for (int k0 = 0; k0 < K; k0 += 32){
    asm volatile("s_waitcnt vmcnt(0)" ::: "memory");   // tile k0 landed in buf[cur]
    __builtin_amdgcn_sched_barrier(0);
    __builtin_amdgcn_s_barrier();                      // visible to all waves
    __builtin_amdgcn_sched_barrier(0);
    if (k0 + 32 < K){                                  // prefetch next tile -> buf[cur^1]
      char* An = (char*)At + (cur^1)*8192 + wave*1024;
      char* Bn = (char*)Bt + (cur^1)*8192 + wave*1024;
      gload16(gA0, An); gload16(gA1, An + 4096);
      gload16(gB0, Bn); gload16(gB1, Bn + 4096);
      gA0 += 32; gA1 += 32; gB0 += 32; gB1 += 32;
    }
    short8 af[4], bfr[4];
    #pragma unroll
    for (int t = 0; t < 4; t++){
      af[t]  = *(const short8*)&At[cur*4096 + (moff + t*16 + l16)*32 + quad*8];
      bfr[t] = *(const short8*)&Bt[cur*4096 + (noff + t*16 + l16)*32 + quad*8];
    }
    #pragma unroll
    for (int mt = 0; mt < 4; mt++)
      #pragma unroll
      for (int nt = 0; nt < 4; nt++)
        acc[mt][nt] = mfma16(bfr[nt], af[mt], acc[mt][nt]);   // C^T fragments
    asm volatile("s_waitcnt lgkmcnt(0)" ::: "memory"); // all reads of buf[cur] serviced
    __builtin_amdgcn_sched_barrier(0);
    __builtin_amdgcn_s_barrier();                      // safe to overwrite buf[cur] next iter
    __builtin_amdgcn_sched_barrier(0);
    cur ^= 1;
  }

  // epilogue: C^T frag -> lane holds act-row = l16, 4 consecutive channels (reg)
  #pragma unroll
  for (int mt = 0; mt < 4; mt++){
    #pragma unroll
    for (int nt = 0; nt < 4; nt++){
      floatx4 v = acc[mt][nt];
      if (z < 2){
        const int s   = m0 + moff + mt*16 + l16;
        const int ch0 = n0 + noff + nt*16 + quad*4;
        const float4 b4 = *(const float4*)&bias[ch0];
        uint2 pk;
        pk.x = pk2bf((v[0] + b4.x)*qs, (v[1] + b4.y)*qs);
        pk.y = pk2bf((v[2] + b4.z)*qs, (v[3] + b4.w)*qs);
        *(unsigned long long*)&outp[(long)s*1024 + ch0] = *(unsigned long long*)&pk;
      } else {
        const int ch = m0 + moff + mt*16 + l16;
        const int s0 = n0 + noff + nt*16 + quad*4;
        const float bb = bias[ch];
        uint2 pk;
        pk.x = pk2bf(v[0] + bb, v[1] + bb);
        pk.y = pk2bf(v[2] + bb, v[3] + bb);
        *(unsigned long long*)&outp[outAdj + (long)ch*2048 + s0] = *(unsigned long long*)&pk;
      }
    }
  }
}

// ---------------- output projection GEMM, 128x64 tiles, global_load_lds staging ----------------
// grid (32 m, 16 n) = 512 blocks; XCD = bx%8 stripes M (A-panel L2-resident).
__global__ __launch_bounds__(256, 2)
void gemm_o_kernel(const ushort_t* __restrict__ A, const ushort_t* __restrict__ BT,
                   const float* __restrict__ bias, float* __restrict__ outf)
{
  __shared__ ushort_t At[2*4096];
  __shared__ ushort_t Bt[2*2048];
  const int tid = threadIdx.x;
  const int wave = tid >> 6, lane = tid & 63;
  const int quad = lane >> 4, l16 = lane & 15;
  const int m0 = blockIdx.x * 128, n0 = blockIdx.y * 64;
  const int K = 1024;

  const int c0 = tid, c1 = 256 + tid;
  const ushort_t* gA0 = A  + (long)(m0 + (c0 >> 2))*K + (c0 & 3)*8;
  const ushort_t* gA1 = A  + (long)(m0 + (c1 >> 2))*K + (c1 & 3)*8;
  const ushort_t* gB0 = BT + (long)(n0 + (c0 >> 2))*K + (c0 & 3)*8;   // 64 rows

  floatx4 acc[4][2];
  #pragma unroll
  for (int mt = 0; mt < 4; mt++)
    #pragma unroll
    for (int nt = 0; nt < 2; nt++)
      acc[mt][nt] = (floatx4){0.f, 0.f, 0.f, 0.f};

  // prologue: issue tile-0 loads into buf 0
  {
    char* Ad = (char*)At + wave*1024;
    char* Bd = (char*)Bt + wave*1024;
    gload16(gA0, Ad); gload16(gA1, Ad + 4096);
    gload16(gB0, Bd);
    gA0 += 32; gA1 += 32; gB0 += 32;
  }

  const int moff = (wave & 1) * 64, noff = (wave >> 1) * 32;
  int cur = 0;
  for (int k0 = 0; k0 < K; k0 += 32){
    asm volatile("s_waitcnt vmcnt(0)" ::: "memory");
    __builtin_amdgcn_sched_barrier(0);
    __builtin_amdgcn_s_barrier();
    __builtin_amdgcn_sched_barrier(0);
    if (k0 + 32 < K){
      char* An = (char*)At + (cur^1)*8192 + wave*1024;
      char* Bn = (char*)Bt + (cur^1)*4096 + wave*1024;
      gload16(gA0, An); gload16(gA1, An + 4096);
      gload16(gB0, Bn);
      gA0 += 32; gA1 += 32; gB0 += 32;
    }
    short8 af[4], bfr[2];
    #pragma unroll
    for (int t = 0; t < 4; t++)
      af[t]  = *(const short8*)&At[cur*4096 + (moff + t*16 + l16)*32 + quad*8];
    #pragma unroll
    for (int t = 0; t < 2; t++)
      bfr[t] = *(const short8*)&Bt[cur*2048 + (noff + t*16 + l16)*32 + quad*8];
    #pragma unroll
    for (int mt = 0; mt < 4; mt++)
      #pragma unroll
      for (int nt = 0; nt < 2; nt++)
        acc[mt][nt] = mfma16(bfr[nt], af[mt], acc[mt][nt]);   // C^T fragments
    asm volatile("s_waitcnt lgkmcnt(0)" ::: "memory");
    __builtin_amdgcn_sched_barrier(0);
    __builtin_amdgcn_s_barrier();
    __builtin_amdgcn_sched_barrier(0);
    cur ^= 1;
  }

  // epilogue: lane holds s = l16, 4 consecutive out channels -> float4 store
  #pragma unroll
  for (int mt = 0; mt < 4; mt++){
    #pragma unroll
    for (int nt = 0; nt < 2; nt++){
      const int s   = m0 + moff + mt*16 + l16;
      const int ch0 = n0 + noff + nt*16 + quad*4;
      const float4 b4 = *(const float4*)&bias[ch0];
      float4 o;
      o.x = acc[mt][nt][0] + b4.x;
      o.y = acc[mt][nt][1] + b4.y;
      o.z = acc[mt][nt][2] + b4.z;
      o.w = acc[mt][nt][3] + b4.w;
      *(float4*)&outf[(long)s*1024 + ch0] = o;
    }
  }
}

// softmax + pack for one q-subtile's 8 scores (zA holds s_local h=0, zB h=1).
// Uses enclosing-scope `uni` and `quad`. All scalars -> no runtime-indexed arrays (rule #20).
#define SM_PB(zA_, zB_, wv_, lsum_, pb_)                              \
  {                                                                   \
    float p0 = __builtin_amdgcn_exp2f((zA_)[0]);                      \
    float p1 = __builtin_amdgcn_exp2f((zA_)[1]);                      \
    float p2 = __builtin_amdgcn_exp2f((zA_)[2]);                      \
    float p3 = __builtin_amdgcn_exp2f((zA_)[3]);                      \
    float p4 = __builtin_amdgcn_exp2f((zB_)[0]);                      \
    float p5 = __builtin_amdgcn_exp2f((zB_)[1]);                      \
    float p6 = __builtin_amdgcn_exp2f((zB_)[2]);                      \
    float p7 = __builtin_amdgcn_exp2f((zB_)[3]);                      \
    if (__builtin_expect(!uni, 0)){                                   \
      const int sh_ = quad*8;                                         \
      p0 = (((wv_) >> (sh_+0)) & 1u) ? p0 : 0.f;                      \
      p1 = (((wv_) >> (sh_+1)) & 1u) ? p1 : 0.f;                      \
      p2 = (((wv_) >> (sh_+2)) & 1u) ? p2 : 0.f;                      \
      p3 = (((wv_) >> (sh_+3)) & 1u) ? p3 : 0.f;                      \
      p4 = (((wv_) >> (sh_+4)) & 1u) ? p4 : 0.f;                      \
      p5 = (((wv_) >> (sh_+5)) & 1u) ? p5 : 0.f;                      \
      p6 = (((wv_) >> (sh_+6)) & 1u) ? p6 : 0.f;                      \
      p7 = (((wv_) >> (sh_+7)) & 1u) ? p7 : 0.f;                      \
    }                                                                 \
    lsum_ += ((p0 + p1) + (p2 + p3)) + ((p4 + p5) + (p6 + p7));       \
    unsigned pk0_ = pk2bf(p0, p1);                                    \
    unsigned pk1_ = pk2bf(p2, p3);                                    \
    unsigned pk2_ = pk2bf(p4, p5);                                    \
    unsigned pk3_ = pk2bf(p6, p7);                                    \
    unsigned tmp_[4] = {pk0_, pk1_, pk2_, pk3_};                      \
    __builtin_memcpy(&(pb_), tmp_, 16);                               \
  }

// ---------------- flash attention: split-s, global_load_lds staging, counted vmcnt ----------------
// (ROUND-4/6 KERNEL, VERBATIM — verified 61.5-62.6 µs, 0 bank conflicts, clean WRITE_SIZE.
//  Measured optimum of 7 attn variants: occupancy capped by VGPR at 4 waves/SIMD (r5),
//  barrier removal regresses (r7), conflicts/traffic/buffering all exonerated (r1/r4/r6).)
__global__ __launch_bounds__(512, 4)
void flash_attn_kernel(const ushort_t* __restrict__ Qp, const ushort_t* __restrict__ Kp,
                       const ushort_t* __restrict__ Vt, const unsigned* __restrict__ mb,
                       ushort_t* __restrict__ aout)
{
  // K region bytes [0,32768): [half][buf][64][64] shorts. V region bytes [32768,65536): same.
  // Merge overlay reuses bytes [0,34816) after the main loop.
  __shared__ __align__(16) unsigned char smem_raw[65536];
  ushort_t* KBs = (ushort_t*)smem_raw;
  ushort_t* VBs = KBs + 16384;                 // shorts
  float* mO = (float*)smem_raw;                // [w4][sub2][ht4][lane64] float4 = 32 KB
  float* mL = (float*)(smem_raw + 32768);      // [w4][sub2][lane64] float = 2 KB

  const int tid = threadIdx.x, wave = tid >> 6, lane = tid & 63;
  const int quad = lane >> 4, l16 = lane & 15;
  const int shalf = wave >> 2, w = wave & 3;
  const int bh = blockIdx.x, qt = blockIdx.y;
  const int b = bh >> 4, h = bh & 15;

  const ushort_t* VB = Vt + (long)bh*131072;
  const int q0 = qt*128 + w*32;

  // ---- staging source addresses (per lane), LDS dest (per wave, linear) ----
  // wave covers LDS rows w*16 + inst*8 + (lane>>3), chunk cl = lane&7; 2 insts each for K,V.
  const int l8 = lane >> 3, cl = lane & 7;
  const int r0 = w*16 + l8;                    // bit3 == 0
  const int sr0 = (r0 & 35) | ((r0 & 4) << 1) | ((r0 & 16) >> 2);   // inverse perm (r0&8==0)
  const int cg = cl ^ l8;                      // chunk swizzle: cl ^ (row&7), row&7 = l8
  const ushort_t* kp0 = Kp + ((long)b*2048 + shalf*1024 + sr0)*1024 + h*64 + cg*8;
  const ushort_t* kp1 = kp0 + 16384;           // r0|8 -> sr0+16 rows
  const ushort_t* vp0 = VB + (long)r0*2048 + shalf*1024 + cg*8;
  const ushort_t* vp1 = vp0 + 16384;           // +8 hd rows
  const int kdo = shalf*16384 + w*2048;        // byte offsets into K region
  const int vdo = 32768 + shalf*16384 + w*2048;

  // prologue: issue tile-0 loads into buf 0 (4 gload_lds per wave, in flight under Q loads)
  {
    char* kd = (char*)smem_raw + kdo;
    gload16(kp0, kd); gload16(kp1, kd + 1024);
    char* vd = (char*)smem_raw + vdo;
    gload16(vp0, vd); gload16(vp1, vd + 1024);
    kp0 += 65536; kp1 += 65536; vp0 += 64; vp1 += 64;
  }

  // Q fragments (B operand of S^T: n=q=l16, k=hd), pre-scaled by log2(e)/8 in GEMM.
  short8 qfA0, qfA1, qfB0, qfB1;
  {
    const long qrowA = ((long)b*2048 + q0 + l16)*1024 + h*64;
    qfA0 = *(const short8*)&Qp[qrowA +      quad*8];
    qfA1 = *(const short8*)&Qp[qrowA + 32 + quad*8];
    const long qrowB = qrowA + 16*1024;
    qfB0 = *(const short8*)&Qp[qrowB +      quad*8];
    qfB1 = *(const short8*)&Qp[qrowB + 32 + quad*8];
  }

  floatx4 accA[4], accB[4];
  #pragma unroll
  for (int ht = 0; ht < 4; ht++){
    accA[ht] = (floatx4){0.f,0.f,0.f,0.f};
    accB[ht] = (floatx4){0.f,0.f,0.f,0.f};
  }
  float lsA = 0.f, lsB = 0.f;

  const uint2* mb2 = (const uint2*)mb;
  const long mbase = (long)b*2048 + q0;
  const int sw8 = l16 & 7;                     // read-side chunk swizzle
  const int kc0 = (quad ^ sw8) * 8;            // K chunk offsets (shorts)
  const int kc1 = kc0 ^ 32;

  int cur = 0;
  for (int st = 0; st < 16; st++){
    // mask words first (counted in the vmcnt budget; pinned above the prefetch)
    const uint2 mwA = mb2[(mbase +      l16)*32 + shalf*16 + st];
    const uint2 mwB = mb2[(mbase + 16 + l16)*32 + shalf*16 + st];
    __builtin_amdgcn_sched_barrier(0);
    if (st < 15){                              // prefetch tile st+1 into buf[cur^1]
      char* kd = (char*)smem_raw + kdo + (cur^1)*8192;
      gload16(kp0, kd); gload16(kp1, kd + 1024);
      char* vd = (char*)smem_raw + vdo + (cur^1)*8192;
      gload16(vp0, vd); gload16(vp1, vd + 1024);
      kp0 += 65536; kp1 += 65536; vp0 += 64; vp1 += 64;
      asm volatile("s_waitcnt vmcnt(6)" ::: "memory");   // tile-cur done; 4 prefetch + 2 mask in flight
    } else {
      asm volatile("s_waitcnt vmcnt(0)" ::: "memory");
    }
    __builtin_amdgcn_s_barrier();              // all waves' tile-cur data in LDS
    __builtin_amdgcn_sched_barrier(0);         // no ds_read hoists above the barrier

    const ushort_t* Kt = KBs + shalf*8192 + cur*4096;
    const ushort_t* Vp = VBs + shalf*8192 + cur*4096;
    const bool uni = __all((mwA.x & mwA.y & mwB.x & mwB.y) == 0xFFFFFFFFu);

    #pragma unroll
    for (int c = 0; c < 2; c++){
      const int rA = (c*2    )*16 + l16;       // permuted-space rows
      const int rB = (c*2 + 1)*16 + l16;
      short8 kA0 = *(const short8*)&Kt[rA*64 + kc0];
      short8 kA1 = *(const short8*)&Kt[rA*64 + kc1];
      short8 kB0 = *(const short8*)&Kt[rB*64 + kc0];
      short8 kB1 = *(const short8*)&Kt[rB*64 + kc1];

      // subtile A scores -> probabilities
      floatx4 zA = (floatx4){0.f,0.f,0.f,0.f};
      zA = mfma16(kA0, qfA0, zA);
      zA = mfma16(kA1, qfA1, zA);
      floatx4 zB = (floatx4){0.f,0.f,0.f,0.f};
      zB = mfma16(kB0, qfA0, zB);
      zB = mfma16(kB1, qfA1, zB);
      const unsigned wvA = c ? mwA.y : mwA.x;
      short8 pbA;
      SM_PB(zA, zB, wvA, lsA, pbA);

      // subtile B scores -> probabilities (reuse z regs)
      zA = (floatx4){0.f,0.f,0.f,0.f};
      zA = mfma16(kA0, qfB0, zA);
      zA = mfma16(kA1, qfB1, zA);
      zB = (floatx4){0.f,0.f,0.f,0.f};
      zB = mfma16(kB0, qfB0, zB);
      zB = mfma16(kB1, qfB1, zB);
      const unsigned wvB = c ? mwB.y : mwB.x;
      short8 pbB;
      SM_PB(zA, zB, wvB, lsB, pbB);

      // PV: V^T A-frag loaded once per ht, feeds both subtiles (full-rate K=32)
      const int vcs = ((c*4 + quad) ^ sw8) * 8;
      #pragma unroll
      for (int ht = 0; ht < 4; ht++){
        const short8 vf = *(const short8*)&Vp[(ht*16 + l16)*64 + vcs];
        accA[ht] = mfma16(vf, pbA, accA[ht]);
        accB[ht] = mfma16(vf, pbB, accB[ht]);
      }
    }

    asm volatile("s_waitcnt lgkmcnt(0)" ::: "memory");  // all reads of buf[cur] serviced
    __builtin_amdgcn_sched_barrier(0);
    __builtin_amdgcn_s_barrier();              // safe for next iter to overwrite buf[cur]
    __builtin_amdgcn_sched_barrier(0);
    cur ^= 1;
  }

  // lsum: quads hold disjoint s-partials of the same q=l16
  lsA += __shfl_xor(lsA, 16);
  lsA += __shfl_xor(lsA, 32);
  lsB += __shfl_xor(lsB, 16);
  lsB += __shfl_xor(lsB, 32);

  // split-s combine through LDS (exact: one-pass exp2 partials just add)
  __syncthreads();                        // vmcnt already 0; safe to overlay staging buffers
  if (shalf == 1){
    #pragma unroll
    for (int ht = 0; ht < 4; ht++){
      *(floatx4*)&mO[((((w*2 + 0)*4 + ht)*64) + lane)*4] = accA[ht];
      *(floatx4*)&mO[((((w*2 + 1)*4 + ht)*64) + lane)*4] = accB[ht];
    }
    mL[(w*2 + 0)*64 + lane] = lsA;
    mL[(w*2 + 1)*64 + lane] = lsB;
  }
  __syncthreads();
  if (shalf == 0){
    const float invA = 1.0f / (lsA + mL[(w*2 + 0)*64 + lane]);
    const float invB = 1.0f / (lsB + mL[(w*2 + 1)*64 + lane]);
    const long rowoA = ((long)b*2048 + q0 + l16)*1024 + h*64;
    const long rowoB = rowoA + 16*1024;
    #pragma unroll
    for (int ht = 0; ht < 4; ht++){
      const floatx4 oA = *(const floatx4*)&mO[((((w*2 + 0)*4 + ht)*64) + lane)*4];
      uint2 pkA;
      pkA.x = pk2bf((accA[ht][0] + oA[0])*invA, (accA[ht][1] + oA[1])*invA);
      pkA.y = pk2bf((accA[ht][2] + oA[2])*invA, (accA[ht][3] + oA[3])*invA);
      *(unsigned long long*)&aout[rowoA + ht*16 + quad*4] = *(unsigned long long*)&pkA;
      const floatx4 oB = *(const floatx4*)&mO[((((w*2 + 1)*4 + ht)*64) + lane)*4];
      uint2 pkB;
      pkB.x = pk2bf((accB[ht][0] + oB[0])*invB, (accB[ht][1] + oB[1])*invB);
      pkB.y = pk2bf((accB[ht][2] + oB[2])*invB, (accB[ht][3] + oB[3])*invB);
      *(unsigned long long*)&aout[rowoB + ht*16 + quad*4] = *(unsigned long long*)&pkB;
    }
  }
}

extern "C" void kernel_launch(void* const* d_in, const int* in_sizes, int n_in,
                              void* d_out, int out_size, void* d_ws, size_t ws_size,
                              hipStream_t stream) {
  const float* dec  = (const float*)d_in[0];
  const float* enc  = (const float*)d_in[1];
  const int*   mask = (const int*)d_in[2];
  const float* Wq   = (const float*)d_in[3];
  const float* bq   = (const float*)d_in[4];
  const float* Wk   = (const float*)d_in[5];
  const float* bk   = (const float*)d_in[6];
  const float* Wv   = (const float*)d_in[7];
  const float* bv   = (const float*)d_in[8];
  const float* Wo   = (const float*)d_in[9];
  const float* bo   = (const float*)d_in[10];
  float* out = (float*)d_out;

  // workspace layout (bf16 = ushort). Total ~51.4 MB.
  ushort_t* ws   = (ushort_t*)d_ws;
  ushort_t* encb = ws;                    // [4096][1024]; reused as attn output after Q-proj
  ushort_t* decb = encb + 4194304;        // [4096][1024]
  ushort_t* Qb   = decb + 4194304;        // [4096][1024] plain (col = h*64+hd), pre-scaled
  ushort_t* Kbf  = Qb   + 4194304;        // [4096][1024] plain
  ushort_t* Vtb  = Kbf  + 4194304;        // [B*H][64][2048]
  ushort_t* WqT  = Vtb  + 4194304;        // [1024 c][1024 d]
  ushort_t* WkT  = WqT  + 1048576;
  ushort_t* WvT  = WkT  + 1048576;
  ushort_t* WoT  = WvT  + 1048576;
  unsigned* Mb   = (unsigned*)(WoT + 1048576);  // 262144 u32 = 1 MB bitmask

  // prep: conv + QKV weight transposes only (maskpack + WoT moved into gemm_qkv z=3)
  prep_kernel<<<8960, 256, 0, stream>>>(enc, dec, Wq, Wk, Wv,
                                        encb, decb, WqT, WkT, WvT);
  // Q, K, V projections + overlapped maskpack/WoT (z=3): grid (32,8,4)
  gemm_qkv_kernel<<<dim3(32,8,4), 256, 0, stream>>>(encb, decb, WqT, WkT, WvT,
                                                    bq, bk, bv, Qb, Kbf, Vtb,
                                                    mask, (unsigned long long*)Mb,
                                                    Wo, WoT);
  // attention (writes attn bf16 into encb, free after Q-proj); round-4/6 verified kernel
  flash_attn_kernel<<<dim3(32,16,1), 512, 0, stream>>>(Qb, Kbf, Vtb, Mb, encb);
  // out = attn * Wo + bo (fp32), 128x64 tiles (m stripes XCDs)
  gemm_o_kernel<<<dim3(32,16,1), 256, 0, stream>>>(encb, WoT, bo, out);
}

// Round 10
// 244.348 us; speedup vs baseline: 1.1783x; 1.1783x over previous
//
#include <hip/hip_runtime.h>
#include <math.h>
#include <stdint.h>

// Problem constants: B=2, S_DEC=2048, S_ENC=2048, D=1024, H=16, HD=64.
// Reference swaps args: Q <- enc_hidden, K/V <- dec_hidden.

typedef unsigned short ushort_t;
typedef __attribute__((ext_vector_type(8))) short short8;    // 8 x bf16 (4 VGPRs)
typedef __attribute__((ext_vector_type(4))) float floatx4;   // MFMA accumulator

__device__ __forceinline__ ushort_t f2bf(float x){
  unsigned u = __float_as_uint(x);
  u += 0x7fffu + ((u >> 16) & 1u);          // RNE
  return (ushort_t)(u >> 16);
}
__device__ __forceinline__ unsigned pk2bf(float a, float b){
#if __has_builtin(__builtin_amdgcn_cvt_pk_bf16_f32)
  typedef __attribute__((ext_vector_type(2))) __bf16 bf2_t;
  bf2_t r = __builtin_amdgcn_cvt_pk_bf16_f32(a, b);
  return *(unsigned*)&r;
#else
  return (unsigned)f2bf(a) | ((unsigned)f2bf(b) << 16);
#endif
}
__device__ __forceinline__ floatx4 mfma16(short8 a, short8 b, floatx4 c){
  return __builtin_amdgcn_mfma_f32_16x16x32_bf16(a, b, c, 0, 0, 0);
}
// direct HBM -> LDS, 16 B per lane; LDS dest = wave-uniform base + lane*16 (linear).
__device__ __forceinline__ void gload16(const void* g, void* l){
  __builtin_amdgcn_global_load_lds((const __attribute__((address_space(1))) void*)g,
                                   (__attribute__((address_space(3))) void*)l, 16, 0, 0);
}

// ---------------- fused prep: conv + weight transposes + maskpack, one dispatch ----------------
// (ROUND-8 STRUCTURE RESTORED — round 9's z=3 overlap made 224 maskpack blocks a 100 µs
//  straggler inside gemm_qkv. Parallel maskpack here is the measured-better layout.)
// block ranges: [0,8192) conv enc/dec; [8192,8960) QKV weight transpose;
// [8960,9216) Wo transpose; [9216,41984) maskpack.
__global__ __launch_bounds__(256)
void prep_kernel(const float* __restrict__ enc, const float* __restrict__ dec,
                 const float* __restrict__ Wq, const float* __restrict__ Wk,
                 const float* __restrict__ Wv, const float* __restrict__ Wo,
                 const int* __restrict__ mask,
                 ushort_t* __restrict__ encb, ushort_t* __restrict__ decb,
                 ushort_t* __restrict__ WqT, ushort_t* __restrict__ WkT,
                 ushort_t* __restrict__ WvT, ushort_t* __restrict__ WoT,
                 unsigned long long* __restrict__ mb)
{
  __shared__ float t[64][65];
  const int bx = blockIdx.x, tid = threadIdx.x;
  if (bx < 8192){                      // fp32 -> bf16 casts
    const float* src = (bx < 4096) ? enc : dec;
    ushort_t*    dst = (bx < 4096) ? encb : decb;
    int i = ((bx & 4095) * 256 + tid) * 4;
    const float4 v = *(const float4*)(src + i);
    unsigned long long p = (unsigned long long)pk2bf(v.x, v.y)
                         | ((unsigned long long)pk2bf(v.z, v.w) << 32);
    *(unsigned long long*)(dst + i) = p;
  } else if (bx < 8960){               // QKV weight transpose: Wx[h][1024 d][64 k] -> WxT[(h*64+k)][1024 d]
    const int id = bx - 8192;          // 768 = 48 z * 16 y
    const int zz = id >> 4, yy = id & 15;
    const int which = zz >> 4, head = zz & 15;
    const float* src = (which == 0) ? Wq : (which == 1) ? Wk : Wv;
    ushort_t*    dst = (which == 0) ? WqT : (which == 1) ? WkT : WvT;
    const long sb = (long)head * 65536;
    const int r0 = yy * 64;
    #pragma unroll
    for (int i = 0; i < 4; i++){       // 1024 float4-chunks = 64 rows x 16 chunks
      int idx = i*256 + tid;
      int r = idx >> 4, c4 = idx & 15;
      const float4 v = *(const float4*)&src[sb + (long)(r0 + r)*64 + c4*4];
      t[r][c4*4+0] = v.x; t[r][c4*4+1] = v.y;
      t[r][c4*4+2] = v.z; t[r][c4*4+3] = v.w;
    }
    __syncthreads();
    #pragma unroll
    for (int i = 0; i < 4; i++){       // 1024 u64-chunks = 64 cols x 16 row-quads
      int idx = i*256 + tid;
      int cr = idx >> 4, rq = idx & 15;
      unsigned long long p =
          (unsigned long long)pk2bf(t[rq*4+0][cr], t[rq*4+1][cr])
        | ((unsigned long long)pk2bf(t[rq*4+2][cr], t[rq*4+3][cr]) << 32);
      *(unsigned long long*)&dst[sb + (long)cr*1024 + r0 + rq*4] = p;
    }
  } else if (bx < 9216){               // Wo [1024 d][1024 e] -> WoT[e][d]
    const int id = bx - 8960;          // 256 = 16 x * 16 y
    const int r0 = (id >> 4) * 64, c0 = (id & 15) * 64;
    #pragma unroll
    for (int i = 0; i < 4; i++){
      int idx = i*256 + tid;
      int r = idx >> 4, c4 = idx & 15;
      const float4 v = *(const float4*)&Wo[(long)(r0 + r)*1024 + c0 + c4*4];
      t[r][c4*4+0] = v.x; t[r][c4*4+1] = v.y;
      t[r][c4*4+2] = v.z; t[r][c4*4+3] = v.w;
    }
    __syncthreads();
    #pragma unroll
    for (int i = 0; i < 4; i++){
      int idx = i*256 + tid;
      int cr = idx >> 4, rq = idx & 15;
      unsigned long long p =
          (unsigned long long)pk2bf(t[rq*4+0][cr], t[rq*4+1][cr])
        | ((unsigned long long)pk2bf(t[rq*4+2][cr], t[rq*4+3][cr]) << 32);
      *(unsigned long long*)&WoT[(long)(c0 + cr)*1024 + r0 + rq*4] = p;
    }
  } else {                             // mask -> bitmask (bit s of u64 word (b*2048+q)*32 + s/64)
    long gid = (long)(bx - 9216) * 256 + tid;
    unsigned long long bal = __ballot(mask[gid] != 0);
    if ((tid & 63) == 0) mb[gid >> 6] = bal;
  }
}

// ---------------- fused QKV projection GEMM (gload_lds staging + T2 LDS swizzle) ----------------
// grid (32 m, 8 n, 3). z=0: Q = (enc*WqT+bq)*Cscale; z=1: K = dec*WkT+bk; z=2: remapped
// 8x16x2 computing V^T = WvT*dec^T + bv (out [bh][64][2048]).
// ROUND-10 (T2 fix): r9's counters exposed 3.2M SQ_LDS_BANK_CONFLICT — the [128][32]-short
// tile read as ds_read_b128 per row puts 16 lanes on 2 banks (8-way). Fix per rule #21
// (gload_lds dest is linear): physical chunk j holds global chunk j ^ ((row>>1)&3) —
// pre-swizzled SOURCE address at staging, swizzled index at read. Start banks become
// 16*(l16&1) + 4*(quad^((l16>>1)&3)) -> all 32 banks covered, 2 lanes/bank (free, m136).
// Read index (l16>>1)&3 is lane-constant (moff/noff multiples of 4 rows): zero loop VALU.
__global__ __launch_bounds__(256, 3)
void gemm_qkv_kernel(const ushort_t* __restrict__ encb, const ushort_t* __restrict__ decb,
                     const ushort_t* __restrict__ WqT, const ushort_t* __restrict__ WkT,
                     const ushort_t* __restrict__ WvT,
                     const float* __restrict__ bq, const float* __restrict__ bk,
                     const float* __restrict__ bv,
                     ushort_t* __restrict__ Qb, ushort_t* __restrict__ Kbf,
                     ushort_t* __restrict__ Vtb)
{
  __shared__ ushort_t At[2*4096];
  __shared__ ushort_t Bt[2*4096];
  const int tid = threadIdx.x;
  const int wave = tid >> 6, lane = tid & 63;
  const int quad = lane >> 4, l16 = lane & 15;
  const int z = blockIdx.z;
  const ushort_t *A, *BT; const float* bias; ushort_t* outp;
  int m0, n0; long outAdj = 0;
  float qs = 1.0f;
  if (z == 0){ A = encb; BT = WqT; bias = bq; outp = Qb;  m0 = blockIdx.x*128; n0 = blockIdx.y*128;
               qs = 0.18033688011112042f; }   // log2(e)/sqrt(64) folded into Q
  else if (z == 1){ A = decb; BT = WkT; bias = bk; outp = Kbf; m0 = blockIdx.x*128; n0 = blockIdx.y*128; }
  else {
    int id = blockIdx.x*8 + blockIdx.y;     // 0..255
    int vb = id >> 7, rem = id & 127;
    m0 = ((rem >> 4) & 7) * 128; n0 = (rem & 15) * 128;
    A = WvT; BT = decb + (long)vb*2097152; bias = bv; outp = Vtb; outAdj = (long)vb*2097152;
  }
  const int K = 1024;

  // chunk c -> row c>>2; PHYSICAL col-chunk c&3 holds GLOBAL col-chunk (c&3)^((c>>3)&3)
  const int c0 = tid, c1 = 256 + tid;
  const int j0 = (c0 & 3) ^ ((c0 >> 3) & 3);
  const int j1 = (c1 & 3) ^ ((c1 >> 3) & 3);
  const ushort_t* gA0 = A  + (long)(m0 + (c0 >> 2))*K + j0*8;
  const ushort_t* gA1 = A  + (long)(m0 + (c1 >> 2))*K + j1*8;
  const ushort_t* gB0 = BT + (long)(n0 + (c0 >> 2))*K + j0*8;
  const ushort_t* gB1 = BT + (long)(n0 + (c1 >> 2))*K + j1*8;

  floatx4 acc[4][4];
  #pragma unroll
  for (int mt = 0; mt < 4; mt++)
    #pragma unroll
    for (int nt = 0; nt < 4; nt++)
      acc[mt][nt] = (floatx4){0.f, 0.f, 0.f, 0.f};

  // prologue: issue tile-0 loads into buf 0 (wave-uniform LDS dest + lane*16)
  {
    char* Ad = (char*)At + wave*1024;
    char* Bd = (char*)Bt + wave*1024;
    gload16(gA0, Ad); gload16(gA1, Ad + 4096);
    gload16(gB0, Bd); gload16(gB1, Bd + 4096);
    gA0 += 32; gA1 += 32; gB0 += 32; gB1 += 32;
  }

  const int moff = (wave & 1) * 64, noff = (wave >> 1) * 64;
  const int rsw = (quad ^ ((l16 >> 1) & 3)) * 8;   // swizzled read chunk (lane-constant)
  int cur = 0;
  for (int k0 = 0; k0 < K; k0 += 32){
    asm volatile("s_waitcnt vmcnt(0)" ::: "memory");   // tile k0 landed in buf[cur]
    __builtin_amdgcn_sched_barrier(0);
    __builtin_amdgcn_s_barrier();                      // visible to all waves
    __builtin_amdgcn_sched_barrier(0);
    if (k0 + 32 < K){                                  // prefetch next tile -> buf[cur^1]
      char* An = (char*)At + (cur^1)*8192 + wave*1024;
      char* Bn = (char*)Bt + (cur^1)*8192 + wave*1024;
      gload16(gA0, An); gload16(gA1, An + 4096);
      gload16(gB0, Bn); gload16(gB1, Bn + 4096);
      gA0 += 32; gA1 += 32; gB0 += 32; gB1 += 32;
    }
    short8 af[4], bfr[4];
    #pragma unroll
    for (int t = 0; t < 4; t++){
      af[t]  = *(const short8*)&At[cur*4096 + (moff + t*16 + l16)*32 + rsw];
      bfr[t] = *(const short8*)&Bt[cur*4096 + (noff + t*16 + l16)*32 + rsw];
    }
    #pragma unroll
    for (int mt = 0; mt < 4; mt++)
      #pragma unroll
      for (int nt = 0; nt < 4; nt++)
        acc[mt][nt] = mfma16(bfr[nt], af[mt], acc[mt][nt]);   // C^T fragments
    asm volatile("s_waitcnt lgkmcnt(0)" ::: "memory"); // all reads of buf[cur] serviced
    __builtin_amdgcn_sched_barrier(0);
    __builtin_amdgcn_s_barrier();                      // safe to overwrite buf[cur] next iter
    __builtin_amdgcn_sched_barrier(0);
    cur ^= 1;
  }

  // epilogue: C^T frag -> lane holds act-row = l16, 4 consecutive channels (reg)
  #pragma unroll
  for (int mt = 0; mt < 4; mt++){
    #pragma unroll
    for (int nt = 0; nt < 4; nt++){
      floatx4 v = acc[mt][nt];
      if (z < 2){
        const int s   = m0 + moff + mt*16 + l16;
        const int ch0 = n0 + noff + nt*16 + quad*4;
        const float4 b4 = *(const float4*)&bias[ch0];
        uint2 pk;
        pk.x = pk2bf((v[0] + b4.x)*qs, (v[1] + b4.y)*qs);
        pk.y = pk2bf((v[2] + b4.z)*qs, (v[3] + b4.w)*qs);
        *(unsigned long long*)&outp[(long)s*1024 + ch0] = *(unsigned long long*)&pk;
      } else {
        const int ch = m0 + moff + mt*16 + l16;
        const int s0 = n0 + noff + nt*16 + quad*4;
        const float bb = bias[ch];
        uint2 pk;
        pk.x = pk2bf(v[0] + bb, v[1] + bb);
        pk.y = pk2bf(v[2] + bb, v[3] + bb);
        *(unsigned long long*)&outp[outAdj + (long)ch*2048 + s0] = *(unsigned long long*)&pk;
      }
    }
  }
}

// ---------------- output projection GEMM, 128x64 tiles, gload_lds + T2 swizzle ----------------
// grid (32 m, 16 n) = 512 blocks; XCD = bx%8 stripes M (A-panel L2-resident).
__global__ __launch_bounds__(256, 2)
void gemm_o_kernel(const ushort_t* __restrict__ A, const ushort_t* __restrict__ BT,
                   const float* __restrict__ bias, float* __restrict__ outf)
{
  __shared__ ushort_t At[2*4096];
  __shared__ ushort_t Bt[2*2048];
  const int tid = threadIdx.x;
  const int wave = tid >> 6, lane = tid & 63;
  const int quad = lane >> 4, l16 = lane & 15;
  const int m0 = blockIdx.x * 128, n0 = blockIdx.y * 64;
  const int K = 1024;

  const int c0 = tid, c1 = 256 + tid;
  const int j0 = (c0 & 3) ^ ((c0 >> 3) & 3);
  const int j1 = (c1 & 3) ^ ((c1 >> 3) & 3);
  const ushort_t* gA0 = A  + (long)(m0 + (c0 >> 2))*K + j0*8;
  const ushort_t* gA1 = A  + (long)(m0 + (c1 >> 2))*K + j1*8;
  const ushort_t* gB0 = BT + (long)(n0 + (c0 >> 2))*K + j0*8;   // 64 rows

  floatx4 acc[4][2];
  #pragma unroll
  for (int mt = 0; mt < 4; mt++)
    #pragma unroll
    for (int nt = 0; nt < 2; nt++)
      acc[mt][nt] = (floatx4){0.f, 0.f, 0.f, 0.f};

  // prologue: issue tile-0 loads into buf 0
  {
    char* Ad = (char*)At + wave*1024;
    char* Bd = (char*)Bt + wave*1024;
    gload16(gA0, Ad); gload16(gA1, Ad + 4096);
    gload16(gB0, Bd);
    gA0 += 32; gA1 += 32; gB0 += 32;
  }

  const int moff = (wave & 1) * 64, noff = (wave >> 1) * 32;
  const int rsw = (quad ^ ((l16 >> 1) & 3)) * 8;   // swizzled read chunk (lane-constant)
  int cur = 0;
  for (int k0 = 0; k0 < K; k0 += 32){
    asm volatile("s_waitcnt vmcnt(0)" ::: "memory");
    __builtin_amdgcn_sched_barrier(0);
    __builtin_amdgcn_s_barrier();
    __builtin_amdgcn_sched_barrier(0);
    if (k0 + 32 < K){
      char* An = (char*)At + (cur^1)*8192 + wave*1024;
      char* Bn = (char*)Bt + (cur^1)*4096 + wave*1024;
      gload16(gA0, An); gload16(gA1, An + 4096);
      gload16(gB0, Bn);
      gA0 += 32; gA1 += 32; gB0 += 32;
    }
    short8 af[4], bfr[2];
    #pragma unroll
    for (int t = 0; t < 4; t++)
      af[t]  = *(const short8*)&At[cur*4096 + (moff + t*16 + l16)*32 + rsw];
    #pragma unroll
    for (int t = 0; t < 2; t++)
      bfr[t] = *(const short8*)&Bt[cur*2048 + (noff + t*16 + l16)*32 + rsw];
    #pragma unroll
    for (int mt = 0; mt < 4; mt++)
      #pragma unroll
      for (int nt = 0; nt < 2; nt++)
        acc[mt][nt] = mfma16(bfr[nt], af[mt], acc[mt][nt]);   // C^T fragments
    asm volatile("s_waitcnt lgkmcnt(0)" ::: "memory");
    __builtin_amdgcn_sched_barrier(0);
    __builtin_amdgcn_s_barrier();
    __builtin_amdgcn_sched_barrier(0);
    cur ^= 1;
  }

  // epilogue: lane holds s = l16, 4 consecutive out channels -> float4 store
  #pragma unroll
  for (int mt = 0; mt < 4; mt++){
    #pragma unroll
    for (int nt = 0; nt < 2; nt++){
      const int s   = m0 + moff + mt*16 + l16;
      const int ch0 = n0 + noff + nt*16 + quad*4;
      const float4 b4 = *(const float4*)&bias[ch0];
      float4 o;
      o.x = acc[mt][nt][0] + b4.x;
      o.y = acc[mt][nt][1] + b4.y;
      o.z = acc[mt][nt][2] + b4.z;
      o.w = acc[mt][nt][3] + b4.w;
      *(float4*)&outf[(long)s*1024 + ch0] = o;
    }
  }
}

// softmax + pack for one q-subtile's 8 scores (zA holds s_local h=0, zB h=1).
// Uses enclosing-scope `uni` and `quad`. All scalars -> no runtime-indexed arrays (rule #20).
#define SM_PB(zA_, zB_, wv_, lsum_, pb_)                              \
  {                                                                   \
    float p0 = __builtin_amdgcn_exp2f((zA_)[0]);                      \
    float p1 = __builtin_amdgcn_exp2f((zA_)[1]);                      \
    float p2 = __builtin_amdgcn_exp2f((zA_)[2]);                      \
    float p3 = __builtin_amdgcn_exp2f((zA_)[3]);                      \
    float p4 = __builtin_amdgcn_exp2f((zB_)[0]);                      \
    float p5 = __builtin_amdgcn_exp2f((zB_)[1]);                      \
    float p6 = __builtin_amdgcn_exp2f((zB_)[2]);                      \
    float p7 = __builtin_amdgcn_exp2f((zB_)[3]);                      \
    if (__builtin_expect(!uni, 0)){                                   \
      const int sh_ = quad*8;                                         \
      p0 = (((wv_) >> (sh_+0)) & 1u) ? p0 : 0.f;                      \
      p1 = (((wv_) >> (sh_+1)) & 1u) ? p1 : 0.f;                      \
      p2 = (((wv_) >> (sh_+2)) & 1u) ? p2 : 0.f;                      \
      p3 = (((wv_) >> (sh_+3)) & 1u) ? p3 : 0.f;                      \
      p4 = (((wv_) >> (sh_+4)) & 1u) ? p4 : 0.f;                      \
      p5 = (((wv_) >> (sh_+5)) & 1u) ? p5 : 0.f;                      \
      p6 = (((wv_) >> (sh_+6)) & 1u) ? p6 : 0.f;                      \
      p7 = (((wv_) >> (sh_+7)) & 1u) ? p7 : 0.f;                      \
    }                                                                 \
    lsum_ += ((p0 + p1) + (p2 + p3)) + ((p4 + p5) + (p6 + p7));       \
    unsigned pk0_ = pk2bf(p0, p1);                                    \
    unsigned pk1_ = pk2bf(p2, p3);                                    \
    unsigned pk2_ = pk2bf(p4, p5);                                    \
    unsigned pk3_ = pk2bf(p6, p7);                                    \
    unsigned tmp_[4] = {pk0_, pk1_, pk2_, pk3_};                      \
    __builtin_memcpy(&(pb_), tmp_, 16);                               \
  }

// ---------------- flash attention: split-s, global_load_lds staging, counted vmcnt ----------------
// (ROUND-4/6 KERNEL, VERBATIM — verified 61.5-62.6 µs, 0 bank conflicts, clean WRITE_SIZE.
//  Measured optimum of 7 attn variants: occupancy capped by VGPR at 4 waves/SIMD (r5),
//  barrier removal regresses (r7), conflicts/traffic/buffering all exonerated (r1/r4/r6).)
__global__ __launch_bounds__(512, 4)
void flash_attn_kernel(const ushort_t* __restrict__ Qp, const ushort_t* __restrict__ Kp,
                       const ushort_t* __restrict__ Vt, const unsigned* __restrict__ mb,
                       ushort_t* __restrict__ aout)
{
  // K region bytes [0,32768): [half][buf][64][64] shorts. V region bytes [32768,65536): same.
  // Merge overlay reuses bytes [0,34816) after the main loop.
  __shared__ __align__(16) unsigned char smem_raw[65536];
  ushort_t* KBs = (ushort_t*)smem_raw;
  ushort_t* VBs = KBs + 16384;                 // shorts
  float* mO = (float*)smem_raw;                // [w4][sub2][ht4][lane64] float4 = 32 KB
  float* mL = (float*)(smem_raw + 32768);      // [w4][sub2][lane64] float = 2 KB

  const int tid = threadIdx.x, wave = tid >> 6, lane = tid & 63;
  const int quad = lane >> 4, l16 = lane & 15;
  const int shalf = wave >> 2, w = wave & 3;
  const int bh = blockIdx.x, qt = blockIdx.y;
  const int b = bh >> 4, h = bh & 15;

  const ushort_t* VB = Vt + (long)bh*131072;
  const int q0 = qt*128 + w*32;

  // ---- staging source addresses (per lane), LDS dest (per wave, linear) ----
  // wave covers LDS rows w*16 + inst*8 + (lane>>3), chunk cl = lane&7; 2 insts each for K,V.
  const int l8 = lane >> 3, cl = lane & 7;
  const int r0 = w*16 + l8;                    // bit3 == 0
  const int sr0 = (r0 & 35) | ((r0 & 4) << 1) | ((r0 & 16) >> 2);   // inverse perm (r0&8==0)
  const int cg = cl ^ l8;                      // chunk swizzle: cl ^ (row&7), row&7 = l8
  const ushort_t* kp0 = Kp + ((long)b*2048 + shalf*1024 + sr0)*1024 + h*64 + cg*8;
  const ushort_t* kp1 = kp0 + 16384;           // r0|8 -> sr0+16 rows
  const ushort_t* vp0 = VB + (long)r0*2048 + shalf*1024 + cg*8;
  const ushort_t* vp1 = vp0 + 16384;           // +8 hd rows
  const int kdo = shalf*16384 + w*2048;        // byte offsets into K region
  const int vdo = 32768 + shalf*16384 + w*2048;

  // prologue: issue tile-0 loads into buf 0 (4 gload_lds per wave, in flight under Q loads)
  {
    char* kd = (char*)smem_raw + kdo;
    gload16(kp0, kd); gload16(kp1, kd + 1024);
    char* vd = (char*)smem_raw + vdo;
    gload16(vp0, vd); gload16(vp1, vd + 1024);
    kp0 += 65536; kp1 += 65536; vp0 += 64; vp1 += 64;
  }

  // Q fragments (B operand of S^T: n=q=l16, k=hd), pre-scaled by log2(e)/8 in GEMM.
  short8 qfA0, qfA1, qfB0, qfB1;
  {
    const long qrowA = ((long)b*2048 + q0 + l16)*1024 + h*64;
    qfA0 = *(const short8*)&Qp[qrowA +      quad*8];
    qfA1 = *(const short8*)&Qp[qrowA + 32 + quad*8];
    const long qrowB = qrowA + 16*1024;
    qfB0 = *(const short8*)&Qp[qrowB +      quad*8];
    qfB1 = *(const short8*)&Qp[qrowB + 32 + quad*8];
  }

  floatx4 accA[4], accB[4];
  #pragma unroll
  for (int ht = 0; ht < 4; ht++){
    accA[ht] = (floatx4){0.f,0.f,0.f,0.f};
    accB[ht] = (floatx4){0.f,0.f,0.f,0.f};
  }
  float lsA = 0.f, lsB = 0.f;

  const uint2* mb2 = (const uint2*)mb;
  const long mbase = (long)b*2048 + q0;
  const int sw8 = l16 & 7;                     // read-side chunk swizzle
  const int kc0 = (quad ^ sw8) * 8;            // K chunk offsets (shorts)
  const int kc1 = kc0 ^ 32;

  int cur = 0;
  for (int st = 0; st < 16; st++){
    // mask words first (counted in the vmcnt budget; pinned above the prefetch)
    const uint2 mwA = mb2[(mbase +      l16)*32 + shalf*16 + st];
    const uint2 mwB = mb2[(mbase + 16 + l16)*32 + shalf*16 + st];
    __builtin_amdgcn_sched_barrier(0);
    if (st < 15){                              // prefetch tile st+1 into buf[cur^1]
      char* kd = (char*)smem_raw + kdo + (cur^1)*8192;
      gload16(kp0, kd); gload16(kp1, kd + 1024);
      char* vd = (char*)smem_raw + vdo + (cur^1)*8192;
      gload16(vp0, vd); gload16(vp1, vd + 1024);
      kp0 += 65536; kp1 += 65536; vp0 += 64; vp1 += 64;
      asm volatile("s_waitcnt vmcnt(6)" ::: "memory");   // tile-cur done; 4 prefetch + 2 mask in flight
    } else {
      asm volatile("s_waitcnt vmcnt(0)" ::: "memory");
    }
    __builtin_amdgcn_s_barrier();              // all waves' tile-cur data in LDS
    __builtin_amdgcn_sched_barrier(0);         // no ds_read hoists above the barrier

    const ushort_t* Kt = KBs + shalf*8192 + cur*4096;
    const ushort_t* Vp = VBs + shalf*8192 + cur*4096;
    const bool uni = __all((mwA.x & mwA.y & mwB.x & mwB.y) == 0xFFFFFFFFu);

    #pragma unroll
    for (int c = 0; c < 2; c++){
      const int rA = (c*2    )*16 + l16;       // permuted-space rows
      const int rB = (c*2 + 1)*16 + l16;
      short8 kA0 = *(const short8*)&Kt[rA*64 + kc0];
      short8 kA1 = *(const short8*)&Kt[rA*64 + kc1];
      short8 kB0 = *(const short8*)&Kt[rB*64 + kc0];
      short8 kB1 = *(const short8*)&Kt[rB*64 + kc1];

      // subtile A scores -> probabilities
      floatx4 zA = (floatx4){0.f,0.f,0.f,0.f};
      zA = mfma16(kA0, qfA0, zA);
      zA = mfma16(kA1, qfA1, zA);
      floatx4 zB = (floatx4){0.f,0.f,0.f,0.f};
      zB = mfma16(kB0, qfA0, zB);
      zB = mfma16(kB1, qfA1, zB);
      const unsigned wvA = c ? mwA.y : mwA.x;
      short8 pbA;
      SM_PB(zA, zB, wvA, lsA, pbA);

      // subtile B scores -> probabilities (reuse z regs)
      zA = (floatx4){0.f,0.f,0.f,0.f};
      zA = mfma16(kA0, qfB0, zA);
      zA = mfma16(kA1, qfB1, zA);
      zB = (floatx4){0.f,0.f,0.f,0.f};
      zB = mfma16(kB0, qfB0, zB);
      zB = mfma16(kB1, qfB1, zB);
      const unsigned wvB = c ? mwB.y : mwB.x;
      short8 pbB;
      SM_PB(zA, zB, wvB, lsB, pbB);

      // PV: V^T A-frag loaded once per ht, feeds both subtiles (full-rate K=32)
      const int vcs = ((c*4 + quad) ^ sw8) * 8;
      #pragma unroll
      for (int ht = 0; ht < 4; ht++){
        const short8 vf = *(const short8*)&Vp[(ht*16 + l16)*64 + vcs];
        accA[ht] = mfma16(vf, pbA, accA[ht]);
        accB[ht] = mfma16(vf, pbB, accB[ht]);
      }
    }

    asm volatile("s_waitcnt lgkmcnt(0)" ::: "memory");  // all reads of buf[cur] serviced
    __builtin_amdgcn_sched_barrier(0);
    __builtin_amdgcn_s_barrier();              // safe for next iter to overwrite buf[cur]
    __builtin_amdgcn_sched_barrier(0);
    cur ^= 1;
  }

  // lsum: quads hold disjoint s-partials of the same q=l16
  lsA += __shfl_xor(lsA, 16);
  lsA += __shfl_xor(lsA, 32);
  lsB += __shfl_xor(lsB, 16);
  lsB += __shfl_xor(lsB, 32);

  // split-s combine through LDS (exact: one-pass exp2 partials just add)
  __syncthreads();                        // vmcnt already 0; safe to overlay staging buffers
  if (shalf == 1){
    #pragma unroll
    for (int ht = 0; ht < 4; ht++){
      *(floatx4*)&mO[((((w*2 + 0)*4 + ht)*64) + lane)*4] = accA[ht];
      *(floatx4*)&mO[((((w*2 + 1)*4 + ht)*64) + lane)*4] = accB[ht];
    }
    mL[(w*2 + 0)*64 + lane] = lsA;
    mL[(w*2 + 1)*64 + lane] = lsB;
  }
  __syncthreads();
  if (shalf == 0){
    const float invA = 1.0f / (lsA + mL[(w*2 + 0)*64 + lane]);
    const float invB = 1.0f / (lsB + mL[(w*2 + 1)*64 + lane]);
    const long rowoA = ((long)b*2048 + q0 + l16)*1024 + h*64;
    const long rowoB = rowoA + 16*1024;
    #pragma unroll
    for (int ht = 0; ht < 4; ht++){
      const floatx4 oA = *(const floatx4*)&mO[((((w*2 + 0)*4 + ht)*64) + lane)*4];
      uint2 pkA;
      pkA.x = pk2bf((accA[ht][0] + oA[0])*invA, (accA[ht][1] + oA[1])*invA);
      pkA.y = pk2bf((accA[ht][2] + oA[2])*invA, (accA[ht][3] + oA[3])*invA);
      *(unsigned long long*)&aout[rowoA + ht*16 + quad*4] = *(unsigned long long*)&pkA;
      const floatx4 oB = *(const floatx4*)&mO[((((w*2 + 1)*4 + ht)*64) + lane)*4];
      uint2 pkB;
      pkB.x = pk2bf((accB[ht][0] + oB[0])*invB, (accB[ht][1] + oB[1])*invB);
      pkB.y = pk2bf((accB[ht][2] + oB[2])*invB, (accB[ht][3] + oB[3])*invB);
      *(unsigned long long*)&aout[rowoB + ht*16 + quad*4] = *(unsigned long long*)&pkB;
    }
  }
}

extern "C" void kernel_launch(void* const* d_in, const int* in_sizes, int n_in,
                              void* d_out, int out_size, void* d_ws, size_t ws_size,
                              hipStream_t stream) {
  const float* dec  = (const float*)d_in[0];
  const float* enc  = (const float*)d_in[1];
  const int*   mask = (const int*)d_in[2];
  const float* Wq   = (const float*)d_in[3];
  const float* bq   = (const float*)d_in[4];
  const float* Wk   = (const float*)d_in[5];
  const float* bk   = (const float*)d_in[6];
  const float* Wv   = (const float*)d_in[7];
  const float* bv   = (const float*)d_in[8];
  const float* Wo   = (const float*)d_in[9];
  const float* bo   = (const float*)d_in[10];
  float* out = (float*)d_out;

  // workspace layout (bf16 = ushort). Total ~51.4 MB.
  ushort_t* ws   = (ushort_t*)d_ws;
  ushort_t* encb = ws;                    // [4096][1024]; reused as attn output after Q-proj
  ushort_t* decb = encb + 4194304;        // [4096][1024]
  ushort_t* Qb   = decb + 4194304;        // [4096][1024] plain (col = h*64+hd), pre-scaled
  ushort_t* Kbf  = Qb   + 4194304;        // [4096][1024] plain
  ushort_t* Vtb  = Kbf  + 4194304;        // [B*H][64][2048]
  ushort_t* WqT  = Vtb  + 4194304;        // [1024 c][1024 d]
  ushort_t* WkT  = WqT  + 1048576;
  ushort_t* WvT  = WkT  + 1048576;
  ushort_t* WoT  = WvT  + 1048576;
  unsigned* Mb   = (unsigned*)(WoT + 1048576);  // 262144 u32 = 1 MB bitmask

  // all prep in one dispatch (conv / weight transposes / maskpack) — round-8 structure
  prep_kernel<<<41984, 256, 0, stream>>>(enc, dec, Wq, Wk, Wv, Wo, mask,
                                         encb, decb, WqT, WkT, WvT, WoT,
                                         (unsigned long long*)Mb);
  // Q, K, V projections in one dispatch (768 blocks = 3/CU; m stripes XCDs) + T2 swizzle
  gemm_qkv_kernel<<<dim3(32,8,3), 256, 0, stream>>>(encb, decb, WqT, WkT, WvT,
                                                    bq, bk, bv, Qb, Kbf, Vtb);
  // attention (writes attn bf16 into encb, free after Q-proj); round-4/6 verified kernel
  flash_attn_kernel<<<dim3(32,16,1), 512, 0, stream>>>(Qb, Kbf, Vtb, Mb, encb);
  // out = attn * Wo + bo (fp32), 128x64 tiles (m stripes XCDs) + T2 swizzle
  gemm_o_kernel<<<dim3(32,16,1), 256, 0, stream>>>(encb, WoT, bo, out);
}